// Round 1
// 353.839 us; speedup vs baseline: 1.1797x; 1.1797x over previous
//
#include <hip/hip_runtime.h>
#include <hip/hip_fp16.h>

#define Nn 100000
#define Ee 800000
#define Dd 16
#define Hh 128
#define Oo 3
#define Rr 2
#define HROW 256      // H row: [h_b0(128) | h_b1(128)]
#define Mm (Rr * Nn)
#define CNTB ((Ee + 255) / 256)                        // 3125 place blocks
#define SWB 48
#define INTB ((Nn + 127) / 128)                        // 782 input blocks
#define NT_IN 128
#define FN 16         // nodes per fused-conv block
#define MPAD 516      // LDS M-row stride (halves)
#define OPAD 264      // LDS out-row stride for fused projection

typedef _Float16 half8 __attribute__((ext_vector_type(8)));
typedef _Float16 half4 __attribute__((ext_vector_type(4)));
typedef float floatx4 __attribute__((ext_vector_type(4)));

// ---------------- diagnostic ----------------
__global__ void k_diag(float* out, float v) { out[0] = v; }

// ================= fused prep: direct-place CSR | swizzle | input =================
// All three paths independent -> pure blockIdx partition, no barriers.
// Direct placement: eidx[bucket*cap + atomicAdd(cnt[bucket])] = src. Degrees are
// Poisson(4) over 200K buckets (max ~20); cap=64 -> overflow probability ~0. Stores
// clamped and conv clamps length, so even overflow is memory-safe.
__global__ __launch_bounds__(256) void k_prep_all(
    const int* __restrict__ ei, const int* __restrict__ et,
    int* __restrict__ cnt, int* __restrict__ eidx, int cap,
    const float* __restrict__ r1root, const float* __restrict__ r1w,
    const float* __restrict__ r2root, const float* __restrict__ r2w,
    __half* __restrict__ Bsw1, __half* __restrict__ Bsw2,
    const float* __restrict__ mf, const float* __restrict__ ff,
    const float* __restrict__ W1, const float* __restrict__ b1,
    __half* __restrict__ H) {
    __shared__ float smem[NT_IN * Dd * 2 + Dd * Hh];   // 24 KB (input path only)
    int tid = threadIdx.x;
    int bx = blockIdx.x;

    if (bx < CNTB) {
        // ---- direct placement: one edge per thread ----
        int e = bx * 256 + tid;
        if (e < Ee) {
            int s = ei[e];
            int d = ei[Ee + e];
            int t = et[e];
            int gb = t * Nn + d;
            int pos = atomicAdd(&cnt[gb], 1);
            if (pos < cap) eidx[(size_t)gb * cap + pos] = s;
        }
        return;
    }
    int sb = bx - CNTB;
    if (sb < SWB) {
        // ---- weight swizzle (verified mapping: tile t holds col (l&15)*8+t) ----
        const float* wroot = (sb < 24) ? r1root : r2root;
        const float* wrel = (sb < 24) ? r1w : r2w;
        __half* Bsw = (sb < 24) ? Bsw1 : Bsw2;
        int idx = (sb % 24) * 256 + tid;
        if (idx >= 8 * 12 * 64) return;
        int l = idx & 63;
        int s = (idx >> 6) % 12;
        int t = (idx >> 6) / 12;
        int n = (l & 15) * 8 + t;
        int k0 = s * 32 + (l >> 4) * 8;
        __half tmp[8];
#pragma unroll
        for (int j = 0; j < 8; ++j) {
            int k = k0 + j;
            float v = (k < Hh) ? wroot[k * Hh + n] : wrel[(size_t)(k - Hh) * Hh + n];
            tmp[j] = __float2half(v);
        }
        *(uint4*)(Bsw + (size_t)idx * 8) = *(uint4*)tmp;
        return;
    }
    // ---- input layer: one 128-node tile (verbatim r12/r14 logic) ----
    float* x0s = smem;
    float* x1s = x0s + NT_IN * Dd;
    float* w = x1s + NT_IN * Dd;
    int n0 = (sb - SWB) * NT_IN;
    {
        const float4* src = (const float4*)W1;
        float4* dst = (float4*)w;
        dst[tid] = src[tid];
        dst[tid + 256] = src[tid + 256];
    }
    {
        float4* d0 = (float4*)x0s;
        float4* d1 = (float4*)x1s;
        const float4* mf4 = (const float4*)(mf + (size_t)n0 * Dd);
        const float4* ff4 = (const float4*)(ff + (size_t)n0 * Dd);
        int rem4 = (Nn - n0) * 4;
#pragma unroll
        for (int i = 0; i < 2; ++i) {
            int idx = tid + i * 256;
            float4 v = make_float4(0.f, 0.f, 0.f, 0.f);
            float4 u = v;
            if (idx < rem4) {
                v = mf4[idx];
                float4 f = ff4[idx];
                u = make_float4(f.x - v.x, f.y - v.y, f.z - v.z, f.w - v.w);
            }
            d0[idx] = v;
            d1[idx] = u;
        }
    }
    __syncthreads();
    int j = tid & 127;
    int half = tid >> 7;
    float bj = b1[j];
    for (int nn = half * 64; nn < half * 64 + 64; ++nn) {
        int n = n0 + nn;
        if (n >= Nn) break;
        float a0 = bj, a1 = bj;
#pragma unroll
        for (int k = 0; k < Dd; ++k) {
            float wk = w[k * Hh + j];
            a0 += x0s[nn * Dd + k] * wk;
            a1 += x1s[nn * Dd + k] * wk;
        }
        a0 = a0 > 0.f ? a0 : 0.01f * a0;
        a1 = a1 > 0.f ? a1 : 0.01f * a1;
        H[(size_t)n * HROW + j] = __float2half(a0);
        H[(size_t)n * HROW + Hh + j] = __float2half(a1);
    }
}

// ---------------- fused conv (r12-proven math): reduction-free gather->LDS + MFMA ----
// Bucket edges live at eidx[gb*cap .. gb*cap+min(cnt[gb],cap)); divisor is true cnt.
// Phase A restructure (this rev): half-wave bucket pairing + full metadata hoist.
//  - lanes 0-31 gather relation-0 bucket, lanes 32-63 relation-1 bucket of same node
//    (each lane loads half8 -> 32 lanes cover the 512B row; 8 gathers in flight/wave)
//  - edge lists prefetched with ONE coalesced load per bucket (<=32 edges,
//    P[Poisson(4)>32] ~ 1e-20), distributed per round via __shfl within half-wave
//  - tail/invalid slots read a zeroed 512B row (no predication, no OOB)
__global__ __launch_bounds__(256, 8) void k_conv_f(const __half* __restrict__ Hin,
                                                   __half* __restrict__ Hout,
                                                   const int* __restrict__ cnt,
                                                   const int* __restrict__ eidx, int cap,
                                                   const __half* __restrict__ Bsw,
                                                   const float* __restrict__ bias,
                                                   const __half* __restrict__ zrow,
                                                   int do_final,
                                                   const float* __restrict__ Wo,
                                                   const float* __restrict__ bo,
                                                   float* __restrict__ out) {
    __shared__ __align__(16) char smem[FN * MPAD * 2];   // 16512 B; TM, later TO (aliased)
    __shared__ float WoS[Hh * Oo];
    __shared__ float bS[Oo];
    auto TM = (__half(*)[MPAD])smem;
    auto TO = (__half(*)[OPAD])smem;

    int tid = threadIdx.x;
    int n0 = blockIdx.x * FN;
    int wv = tid >> 6;
    int lane = tid & 63;

    if (do_final) {
        for (int i = tid; i < Hh * Oo; i += 256) WoS[i] = Wo[i];
        if (tid < Oo) bS[tid] = bo[tid];
    }

    // ---- Phase A ----
    int hh32 = lane >> 5;      // half-wave id == relation t
    int sl = lane & 31;        // sublane within half-wave
    const __half* zr = zrow + sl * 8;

    // hoisted metadata: 8 cnt loads + 4 edge-list loads, all concurrent
    int cn0[4], cn1[4], sidx[4];
#pragma unroll
    for (int p = 0; p < 4; ++p) {
        int gb0 = n0 + wv * 4 + p;                       // relation-0 bucket
        cn0[p] = cnt[gb0];
        cn1[p] = cnt[gb0 + Nn];
        sidx[p] = eidx[(size_t)(hh32 * Nn + gb0) * cap + sl];
    }

#pragma unroll
    for (int p = 0; p < 4; ++p) {
        int nl = wv * 4 + p;
        int cn_h = hh32 ? cn1[p] : cn0[p];
        int len = cn_h < 32 ? cn_h : 32;
        int mlr = cn0[p] > cn1[p] ? cn0[p] : cn1[p];
        int maxlen = mlr < 32 ? mlr : 32;

        float2 ac[4];
#pragma unroll
        for (int j = 0; j < 4; ++j) { ac[j].x = 0.f; ac[j].y = 0.f; }

        for (int e = 0; e < maxlen; e += 4) {
            half8 v[4];
#pragma unroll
            for (int u = 0; u < 4; ++u) {
                int s = __shfl(sidx[p], e + u, 32);      // ds_bpermute, cheap
                const __half* rp = ((e + u) < len)
                    ? (Hin + (size_t)s * HROW + sl * 8) : zr;
                v[u] = *(const half8*)(const void*)rp;
            }
#pragma unroll
            for (int u = 0; u < 4; ++u) {
#pragma unroll
                for (int j = 0; j < 4; ++j) {
                    ac[j].x += (float)v[u][2 * j];
                    ac[j].y += (float)v[u][2 * j + 1];
                }
            }
        }

        float iv = 1.0f / fmaxf((float)cn_h, 1.0f);
        __half2 o[4];
#pragma unroll
        for (int j = 0; j < 4; ++j)
            o[j] = __floats2half2_rn(ac[j].x * iv, ac[j].y * iv);
        __half* dst = &TM[nl][hh32 * 256 + sl * 8];      // row stride 1032B: 8B-aligned
        *(uint2*)dst = *(uint2*)&o[0];
        *(uint2*)(dst + 4) = *(uint2*)&o[2];
    }
    __syncthreads();

    // Phase B: MFMA. wave -> branch b = wv>>1, col-half hh = wv&1  (unchanged)
    int b = wv >> 1;
    int hh = wv & 1;
    int quad = lane >> 4;
    int l15 = lane & 15;

    floatx4 acc[4];
#pragma unroll
    for (int t = 0; t < 4; ++t) {
        float bv = bias[l15 * 8 + hh * 4 + t];
        acc[t][0] = bv; acc[t][1] = bv; acc[t][2] = bv; acc[t][3] = bv;
    }

    const __half* hrow = Hin + (size_t)(n0 + l15) * HROW + b * Hh + quad * 8;
#pragma unroll
    for (int s = 0; s < 12; ++s) {
        half8 af;
        if (s < 4)
            af = *(const half8*)(const void*)(hrow + s * 32);
        else
            af = *(const half8*)(const void*)&TM[l15][((s >> 2) - 1) * 256 + b * 128 +
                                                     (s & 3) * 32 + quad * 8];
#pragma unroll
        for (int t = 0; t < 4; ++t) {
            half8 bf = *(const half8*)(const void*)(
                Bsw + ((size_t)((hh * 4 + t) * 12 + s) * 64 + lane) * 8);
            acc[t] = __builtin_amdgcn_mfma_f32_16x16x32_f16(af, bf, acc[t], 0, 0, 0);
        }
    }

    if (!do_final) {
#pragma unroll
        for (int r = 0; r < 4; ++r) {
            int node = n0 + quad * 4 + r;
            __half2 o[2];
            o[0] = __floats2half2_rn(acc[0][r], acc[1][r]);
            o[1] = __floats2half2_rn(acc[2][r], acc[3][r]);
            *(uint2*)(Hout + (size_t)node * HROW + b * Hh + l15 * 8 + hh * 4) = *(uint2*)o;
        }
    } else {
        __syncthreads();  // all TM reads done before aliased TO writes
#pragma unroll
        for (int r = 0; r < 4; ++r) {
            int nl = quad * 4 + r;
            __half2 o[2];
            o[0] = __floats2half2_rn(acc[0][r], acc[1][r]);
            o[1] = __floats2half2_rn(acc[2][r], acc[3][r]);
            *(uint2*)&TO[nl][b * 128 + l15 * 8 + hh * 4] = *(uint2*)o;
        }
        __syncthreads();
        if (tid < FN * Oo) {
            int node = tid / 3;
            int o3 = tid - node * 3;
            float a = bS[o3], m = bS[o3];
            const __half2* row = (const __half2*)TO[node];
#pragma unroll 4
            for (int k2 = 0; k2 < 64; ++k2) {
                float2 v = __half22float2(row[k2]);
                float2 u = __half22float2(row[64 + k2]);
                float w0 = WoS[(2 * k2) * 3 + o3];
                float w1 = WoS[(2 * k2 + 1) * 3 + o3];
                a += v.x * w0 + v.y * w1;
                m += u.x * w0 + u.y * w1;
            }
            out[(size_t)(n0 + node) * 3 + o3] = a * m;
        }
    }
}

// ================= host =================
extern "C" void kernel_launch(void* const* d_in, const int* in_sizes, int n_in,
                              void* d_out, int out_size, void* d_ws, size_t ws_size,
                              hipStream_t stream) {
    const float* mf = (const float*)d_in[0];
    const float* ff = (const float*)d_in[1];
    const float* W1 = (const float*)d_in[2];
    const float* b1 = (const float*)d_in[3];
    const float* rg1_w = (const float*)d_in[4];
    const float* rg1_root = (const float*)d_in[5];
    const float* rg1_b = (const float*)d_in[6];
    const float* rg2_w = (const float*)d_in[7];
    const float* rg2_root = (const float*)d_in[8];
    const float* rg2_b = (const float*)d_in[9];
    const float* Wo = (const float*)d_in[10];
    const float* bo = (const float*)d_in[11];
    const int* ei = (const int*)d_in[12];
    const int* et = (const int*)d_in[13];
    float* out = (float*)d_out;

    const size_t szBsw = (size_t)8 * 12 * 64 * 8 * 2;  // 96 KB

    // layout for a given bucket capacity; cnt region carries a 512B zero-row tail
    auto layoutNeed = [&](int cap, size_t* offs) {
        size_t o = 0;
        auto take = [&](size_t bytes) { size_t r = o; o += (bytes + 15) & ~(size_t)15; return r; };
        offs[0] = take((size_t)Mm * 4 + 512);        // cnt + zero-row
        offs[1] = take((size_t)Mm * cap * 4);        // eidx (fixed-capacity buckets)
        offs[2] = take(szBsw);                       // Bsw1
        offs[3] = take(szBsw);                       // Bsw2
        offs[4] = take((size_t)Nn * HROW * 2);       // H0
        offs[5] = take((size_t)Nn * HROW * 2);       // H1
        return o;
    };

    size_t offs[6];
    int cap = 64;                                    // ~154.7 MB (proven ws >= ~159.6 MB)
    size_t NEED = layoutNeed(cap, offs);
    if (ws_size < NEED) {
        cap = 32;                                    // ~129.1 MB fallback
        NEED = layoutNeed(cap, offs);
        if (ws_size < NEED) {
            k_diag<<<1, 1, 0, stream>>>(out, (float)ws_size);
            return;
        }
    }

    int* cnt = (int*)((char*)d_ws + offs[0]);
    int* eidx = (int*)((char*)d_ws + offs[1]);
    __half* Bsw1 = (__half*)((char*)d_ws + offs[2]);
    __half* Bsw2 = (__half*)((char*)d_ws + offs[3]);
    __half* H0 = (__half*)((char*)d_ws + offs[4]);
    __half* H1 = (__half*)((char*)d_ws + offs[5]);
    const __half* zrow = (const __half*)((char*)d_ws + offs[0] + (size_t)Mm * 4);

    // 4-dispatch pipeline
    hipMemsetAsync(cnt, 0, (size_t)Mm * 4 + 512, stream);
    k_prep_all<<<CNTB + SWB + INTB, 256, 0, stream>>>(ei, et, cnt, eidx, cap,
                                                      rg1_root, rg1_w, rg2_root, rg2_w,
                                                      Bsw1, Bsw2, mf, ff, W1, b1, H0);
    k_conv_f<<<Nn / FN, 256, 0, stream>>>(H0, H1, cnt, eidx, cap, Bsw1, rg1_b, zrow,
                                          0, nullptr, nullptr, nullptr);
    k_conv_f<<<Nn / FN, 256, 0, stream>>>(H1, H0, cnt, eidx, cap, Bsw2, rg2_b, zrow,
                                          1, Wo, bo, out);
}

// Round 2
// 345.058 us; speedup vs baseline: 1.2097x; 1.0254x over previous
//
#include <hip/hip_runtime.h>
#include <hip/hip_fp16.h>

#define Nn 100000
#define Ee 800000
#define Dd 16
#define Hh 128
#define Oo 3
#define Rr 2
#define HROW 256      // H row: [h_b0(128) | h_b1(128)]
#define Mm (Rr * Nn)
#define CNTB ((Ee + 255) / 256)                        // 3125 place blocks
#define SWB 48
#define INTB ((Nn + 127) / 128)                        // 782 input blocks
#define NT_IN 128
#define FN 16         // nodes per fused-conv block
#define MPAD 516      // LDS M-row stride (halves)
#define OPAD 264      // LDS out-row stride for fused projection

typedef _Float16 half8 __attribute__((ext_vector_type(8)));
typedef _Float16 half4 __attribute__((ext_vector_type(4)));
typedef float floatx4 __attribute__((ext_vector_type(4)));

// ---------------- diagnostic ----------------
__global__ void k_diag(float* out, float v) { out[0] = v; }

// ================= fused prep: input | direct-place CSR | swizzle =================
// All three paths independent -> pure blockIdx partition, no barriers, NO LDS.
// Input blocks first (longest jobs); place-path atomic latency backfills under them.
__global__ __launch_bounds__(256) void k_prep_all(
    const int* __restrict__ ei, const int* __restrict__ et,
    int* __restrict__ cnt, int* __restrict__ eidx, int cap,
    const float* __restrict__ r1root, const float* __restrict__ r1w,
    const float* __restrict__ r2root, const float* __restrict__ r2w,
    __half* __restrict__ Bsw1, __half* __restrict__ Bsw2,
    const float* __restrict__ mf, const float* __restrict__ ff,
    const float* __restrict__ W1, const float* __restrict__ b1,
    __half* __restrict__ H) {
    int tid = threadIdx.x;
    int bx = blockIdx.x;

    if (bx < INTB) {
        // ---- input layer: 128-node tile, LDS-free ----
        // w[k][j] loop-invariant per thread -> 16 VGPRs (coalesced loads).
        // x rows are wave-uniform (address independent of lane) -> scalar loads;
        // readfirstlane forces the uniformity proof so s_load is emitted.
        int n0 = bx * NT_IN;
        int j = tid & 127;
        int hf = __builtin_amdgcn_readfirstlane(tid >> 7);
        float wk[Dd];
#pragma unroll
        for (int k = 0; k < Dd; ++k) wk[k] = W1[k * Hh + j];
        float bj = b1[j];
        int nbeg = n0 + hf * 64;
        int nend = nbeg + 64;
        if (nend > Nn) nend = Nn;
#pragma unroll 2
        for (int n = nbeg; n < nend; ++n) {
            const float* xr = mf + (size_t)n * Dd;
            const float* fr = ff + (size_t)n * Dd;
            float a0 = bj, a1 = bj;
#pragma unroll
            for (int k = 0; k < Dd; ++k) {
                float xv = xr[k];
                float fv = fr[k];
                a0 = fmaf(xv, wk[k], a0);          // v_fma: 1 SGPR operand ok
                a1 = fmaf(fv, wk[k], a1);
                a1 = fmaf(-xv, wk[k], a1);         // (fv-xv)*w without 2-SGPR instr
            }
            a0 = a0 > 0.f ? a0 : 0.01f * a0;
            a1 = a1 > 0.f ? a1 : 0.01f * a1;
            H[(size_t)n * HROW + j] = __float2half(a0);
            H[(size_t)n * HROW + Hh + j] = __float2half(a1);
        }
        return;
    }
    int sb = bx - INTB;
    if (sb < CNTB) {
        // ---- direct placement: one edge per thread ----
        // eidx[bucket*cap + atomicAdd(cnt[bucket])] = src. Degrees Poisson(4),
        // cap=64 -> overflow prob ~0; stores clamped, conv clamps length.
        int e = sb * 256 + tid;
        if (e < Ee) {
            int s = ei[e];
            int d = ei[Ee + e];
            int t = et[e];
            int gb = t * Nn + d;
            int pos = atomicAdd(&cnt[gb], 1);
            if (pos < cap) eidx[(size_t)gb * cap + pos] = s;
        }
        return;
    }
    sb -= CNTB;
    {
        // ---- weight swizzle (verified mapping: tile t holds col (l&15)*8+t) ----
        const float* wroot = (sb < 24) ? r1root : r2root;
        const float* wrel = (sb < 24) ? r1w : r2w;
        __half* Bsw = (sb < 24) ? Bsw1 : Bsw2;
        int idx = (sb % 24) * 256 + tid;
        if (idx >= 8 * 12 * 64) return;
        int l = idx & 63;
        int s = (idx >> 6) % 12;
        int t = (idx >> 6) / 12;
        int n = (l & 15) * 8 + t;
        int k0 = s * 32 + (l >> 4) * 8;
        __half tmp[8];
#pragma unroll
        for (int jj = 0; jj < 8; ++jj) {
            int k = k0 + jj;
            float v = (k < Hh) ? wroot[k * Hh + n] : wrel[(size_t)(k - Hh) * Hh + n];
            tmp[jj] = __float2half(v);
        }
        *(uint4*)(Bsw + (size_t)idx * 8) = *(uint4*)tmp;
    }
}

// ---------------- fused conv (r12-proven math): reduction-free gather->LDS + MFMA ----
// Bucket edges live at eidx[gb*cap .. gb*cap+min(cnt[gb],cap)); divisor is true cnt.
// Phase A: half-wave bucket pairing + full metadata hoist (proven last round).
//  - lanes 0-31 gather relation-0 bucket, lanes 32-63 relation-1 bucket of same node
//    (each lane loads half8 -> 32 lanes cover the 512B row; 8 gathers in flight/wave)
//  - edge lists prefetched with ONE coalesced load per bucket (<=32 edges,
//    P[Poisson(4)>32] ~ 1e-20), distributed per round via __shfl within half-wave
//  - tail/invalid slots read a zeroed 512B row (no predication, no OOB)
__global__ __launch_bounds__(256, 8) void k_conv_f(const __half* __restrict__ Hin,
                                                   __half* __restrict__ Hout,
                                                   const int* __restrict__ cnt,
                                                   const int* __restrict__ eidx, int cap,
                                                   const __half* __restrict__ Bsw,
                                                   const float* __restrict__ bias,
                                                   const __half* __restrict__ zrow,
                                                   int do_final,
                                                   const float* __restrict__ Wo,
                                                   const float* __restrict__ bo,
                                                   float* __restrict__ out) {
    __shared__ __align__(16) char smem[FN * MPAD * 2];   // 16512 B; TM, later TO (aliased)
    __shared__ float WoS[Hh * Oo];
    __shared__ float bS[Oo];
    auto TM = (__half(*)[MPAD])smem;
    auto TO = (__half(*)[OPAD])smem;

    int tid = threadIdx.x;
    int n0 = blockIdx.x * FN;
    int wv = tid >> 6;
    int lane = tid & 63;

    if (do_final) {
        for (int i = tid; i < Hh * Oo; i += 256) WoS[i] = Wo[i];
        if (tid < Oo) bS[tid] = bo[tid];
    }

    // ---- Phase A ----
    int hh32 = lane >> 5;      // half-wave id == relation t
    int sl = lane & 31;        // sublane within half-wave
    const __half* zr = zrow + sl * 8;

    // hoisted metadata: 8 cnt loads + 4 edge-list loads, all concurrent
    int cn0[4], cn1[4], sidx[4];
#pragma unroll
    for (int p = 0; p < 4; ++p) {
        int gb0 = n0 + wv * 4 + p;                       // relation-0 bucket
        cn0[p] = cnt[gb0];
        cn1[p] = cnt[gb0 + Nn];
        sidx[p] = eidx[(size_t)(hh32 * Nn + gb0) * cap + sl];
    }

#pragma unroll
    for (int p = 0; p < 4; ++p) {
        int nl = wv * 4 + p;
        int cn_h = hh32 ? cn1[p] : cn0[p];
        int len = cn_h < 32 ? cn_h : 32;
        int mlr = cn0[p] > cn1[p] ? cn0[p] : cn1[p];
        int maxlen = mlr < 32 ? mlr : 32;

        float2 ac[4];
#pragma unroll
        for (int j = 0; j < 4; ++j) { ac[j].x = 0.f; ac[j].y = 0.f; }

        for (int e = 0; e < maxlen; e += 4) {
            half8 v[4];
#pragma unroll
            for (int u = 0; u < 4; ++u) {
                int s = __shfl(sidx[p], e + u, 32);      // ds_bpermute, cheap
                const __half* rp = ((e + u) < len)
                    ? (Hin + (size_t)s * HROW + sl * 8) : zr;
                v[u] = *(const half8*)(const void*)rp;
            }
#pragma unroll
            for (int u = 0; u < 4; ++u) {
#pragma unroll
                for (int j = 0; j < 4; ++j) {
                    ac[j].x += (float)v[u][2 * j];
                    ac[j].y += (float)v[u][2 * j + 1];
                }
            }
        }

        float iv = 1.0f / fmaxf((float)cn_h, 1.0f);
        __half2 o[4];
#pragma unroll
        for (int j = 0; j < 4; ++j)
            o[j] = __floats2half2_rn(ac[j].x * iv, ac[j].y * iv);
        __half* dst = &TM[nl][hh32 * 256 + sl * 8];      // row stride 1032B: 8B-aligned
        *(uint2*)dst = *(uint2*)&o[0];
        *(uint2*)(dst + 4) = *(uint2*)&o[2];
    }
    __syncthreads();

    // Phase B: MFMA. wave -> branch b = wv>>1, col-half hh = wv&1  (unchanged)
    int b = wv >> 1;
    int hh = wv & 1;
    int quad = lane >> 4;
    int l15 = lane & 15;

    floatx4 acc[4];
#pragma unroll
    for (int t = 0; t < 4; ++t) {
        float bv = bias[l15 * 8 + hh * 4 + t];
        acc[t][0] = bv; acc[t][1] = bv; acc[t][2] = bv; acc[t][3] = bv;
    }

    const __half* hrow = Hin + (size_t)(n0 + l15) * HROW + b * Hh + quad * 8;
#pragma unroll
    for (int s = 0; s < 12; ++s) {
        half8 af;
        if (s < 4)
            af = *(const half8*)(const void*)(hrow + s * 32);
        else
            af = *(const half8*)(const void*)&TM[l15][((s >> 2) - 1) * 256 + b * 128 +
                                                     (s & 3) * 32 + quad * 8];
#pragma unroll
        for (int t = 0; t < 4; ++t) {
            half8 bf = *(const half8*)(const void*)(
                Bsw + ((size_t)((hh * 4 + t) * 12 + s) * 64 + lane) * 8);
            acc[t] = __builtin_amdgcn_mfma_f32_16x16x32_f16(af, bf, acc[t], 0, 0, 0);
        }
    }

    if (!do_final) {
#pragma unroll
        for (int r = 0; r < 4; ++r) {
            int node = n0 + quad * 4 + r;
            __half2 o[2];
            o[0] = __floats2half2_rn(acc[0][r], acc[1][r]);
            o[1] = __floats2half2_rn(acc[2][r], acc[3][r]);
            *(uint2*)(Hout + (size_t)node * HROW + b * Hh + l15 * 8 + hh * 4) = *(uint2*)o;
        }
    } else {
        __syncthreads();  // all TM reads done before aliased TO writes
#pragma unroll
        for (int r = 0; r < 4; ++r) {
            int nl = quad * 4 + r;
            __half2 o[2];
            o[0] = __floats2half2_rn(acc[0][r], acc[1][r]);
            o[1] = __floats2half2_rn(acc[2][r], acc[3][r]);
            *(uint2*)&TO[nl][b * 128 + l15 * 8 + hh * 4] = *(uint2*)o;
        }
        __syncthreads();
        if (tid < FN * Oo) {
            int node = tid / 3;
            int o3 = tid - node * 3;
            float a = bS[o3], m = bS[o3];
            const __half2* row = (const __half2*)TO[node];
#pragma unroll 4
            for (int k2 = 0; k2 < 64; ++k2) {
                float2 v = __half22float2(row[k2]);
                float2 u = __half22float2(row[64 + k2]);
                float w0 = WoS[(2 * k2) * 3 + o3];
                float w1 = WoS[(2 * k2 + 1) * 3 + o3];
                a += v.x * w0 + v.y * w1;
                m += u.x * w0 + u.y * w1;
            }
            out[(size_t)(n0 + node) * 3 + o3] = a * m;
        }
    }
}

// ================= host =================
extern "C" void kernel_launch(void* const* d_in, const int* in_sizes, int n_in,
                              void* d_out, int out_size, void* d_ws, size_t ws_size,
                              hipStream_t stream) {
    const float* mf = (const float*)d_in[0];
    const float* ff = (const float*)d_in[1];
    const float* W1 = (const float*)d_in[2];
    const float* b1 = (const float*)d_in[3];
    const float* rg1_w = (const float*)d_in[4];
    const float* rg1_root = (const float*)d_in[5];
    const float* rg1_b = (const float*)d_in[6];
    const float* rg2_w = (const float*)d_in[7];
    const float* rg2_root = (const float*)d_in[8];
    const float* rg2_b = (const float*)d_in[9];
    const float* Wo = (const float*)d_in[10];
    const float* bo = (const float*)d_in[11];
    const int* ei = (const int*)d_in[12];
    const int* et = (const int*)d_in[13];
    float* out = (float*)d_out;

    const size_t szBsw = (size_t)8 * 12 * 64 * 8 * 2;  // 96 KB

    // layout for a given bucket capacity; cnt region carries a 512B zero-row tail
    auto layoutNeed = [&](int cap, size_t* offs) {
        size_t o = 0;
        auto take = [&](size_t bytes) { size_t r = o; o += (bytes + 15) & ~(size_t)15; return r; };
        offs[0] = take((size_t)Mm * 4 + 512);        // cnt + zero-row
        offs[1] = take((size_t)Mm * cap * 4);        // eidx (fixed-capacity buckets)
        offs[2] = take(szBsw);                       // Bsw1
        offs[3] = take(szBsw);                       // Bsw2
        offs[4] = take((size_t)Nn * HROW * 2);       // H0
        offs[5] = take((size_t)Nn * HROW * 2);       // H1
        return o;
    };

    size_t offs[6];
    int cap = 64;                                    // ~154.7 MB (proven ws >= ~159.6 MB)
    size_t NEED = layoutNeed(cap, offs);
    if (ws_size < NEED) {
        cap = 32;                                    // ~129.1 MB fallback
        NEED = layoutNeed(cap, offs);
        if (ws_size < NEED) {
            k_diag<<<1, 1, 0, stream>>>(out, (float)ws_size);
            return;
        }
    }

    int* cnt = (int*)((char*)d_ws + offs[0]);
    int* eidx = (int*)((char*)d_ws + offs[1]);
    __half* Bsw1 = (__half*)((char*)d_ws + offs[2]);
    __half* Bsw2 = (__half*)((char*)d_ws + offs[3]);
    __half* H0 = (__half*)((char*)d_ws + offs[4]);
    __half* H1 = (__half*)((char*)d_ws + offs[5]);
    const __half* zrow = (const __half*)((char*)d_ws + offs[0] + (size_t)Mm * 4);

    // 4-dispatch pipeline
    hipMemsetAsync(cnt, 0, (size_t)Mm * 4 + 512, stream);
    k_prep_all<<<INTB + CNTB + SWB, 256, 0, stream>>>(ei, et, cnt, eidx, cap,
                                                      rg1_root, rg1_w, rg2_root, rg2_w,
                                                      Bsw1, Bsw2, mf, ff, W1, b1, H0);
    k_conv_f<<<Nn / FN, 256, 0, stream>>>(H0, H1, cnt, eidx, cap, Bsw1, rg1_b, zrow,
                                          0, nullptr, nullptr, nullptr);
    k_conv_f<<<Nn / FN, 256, 0, stream>>>(H1, H0, cnt, eidx, cap, Bsw2, rg2_b, zrow,
                                          1, Wo, bo, out);
}